// Round 5
// baseline (126.265 us; speedup 1.0000x reference)
//
#include <hip/hip_runtime.h>
#include <cstddef>

#define BB 16
#define PP 4
#define HH 32
#define WW 32
#define DD 32
#define CC 8

typedef float fx4 __attribute__((ext_vector_type(4)));

// Four voxels per thread (h0..h0+3), one 4-channel half each, software-pipelined:
// loads of voxel v+1/v+2 issued before FMAs of voxel v -> ~16-24 loads in flight.
// Block tile = 4h x 4w x 32d (~26KB gather footprint -> L1-resident corner reuse).
// Branch-free: clamped addresses, zeroed weights for out-of-volume corners.
__global__ __launch_bounds__(256) void resample_kernel(
    const float* __restrict__ fmap,
    const float* __restrict__ theta,
    float* __restrict__ out)
{
    const int bp   = blockIdx.x >> 6;            // 64 blocks per (b,p)
    const int idx  = blockIdx.x & 63;
    const int h0   = (idx >> 3) << 2;            // 8 h-tiles of 4
    const int w0   = (idx & 7) << 2;             // 8 w-tiles of 4
    const int tid  = threadIdx.x;
    const int half = tid & 1;                    // which float4 of the 8 channels
    const int d    = (tid >> 1) & 31;
    const int w    = w0 + (tid >> 6);            // one w per wave

    const float* th = theta + bp * 12;
    const float t0 = th[0], t1 = th[1], t2 = th[2],  t3  = th[3];
    const float t4 = th[4], t5 = th[5], t6 = th[6],  t7  = th[7];
    const float t8 = th[8], t9 = th[9], t10 = th[10], t11 = th[11];

    const float fw = (float)w, fd = (float)d;
    const float* __restrict__ base = fmap + (size_t)bp * (HH * WW * DD * CC) + half * 4;
    float* __restrict__ obase = out + (size_t)bp * (HH * WW * DD * CC)
                                + (size_t)(((h0 * WW) + w) * DD + d) * CC + half * 4;

    unsigned off[4][8];
    float    wgt[4][8];
    fx4      c[4][8];

    auto calc = [&](int v) {
        const float fh = (float)(h0 + v);
        // meshgrid 'xy': grid point is (x=w, y=h, z=d); +2 pad offset
        const float x = fmaf(t0, fw, fmaf(t1, fh, fmaf(t2,  fd, t3 ))) + 2.0f;
        const float y = fmaf(t4, fw, fmaf(t5, fh, fmaf(t6,  fd, t7 ))) + 2.0f;
        const float z = fmaf(t8, fw, fmaf(t9, fh, fmaf(t10, fd, t11))) + 2.0f;

        // faithful: floor -> clip to [0, H+2] in padded coords (all axes H+2)
        const int x0 = min(max((int)floorf(x), 0), HH + 2);
        const int y0 = min(max((int)floorf(y), 0), HH + 2);
        const int z0 = min(max((int)floorf(z), 0), HH + 2);
        const float xd = x - (float)x0, yd = y - (float)y0, zd = z - (float)z0;

        const int ix[2] = { x0 - 2, x0 - 1 };    // x indexes the H axis (ref quirk)
        const int iy[2] = { y0 - 2, y0 - 1 };
        const int iz[2] = { z0 - 2, z0 - 1 };
        const float wxv[2] = { (1.0f - xd) * (((unsigned)ix[0] < (unsigned)HH) ? 1.0f : 0.0f),
                               xd          * (((unsigned)ix[1] < (unsigned)HH) ? 1.0f : 0.0f) };
        const float wyv[2] = { (1.0f - yd) * (((unsigned)iy[0] < (unsigned)WW) ? 1.0f : 0.0f),
                               yd          * (((unsigned)iy[1] < (unsigned)WW) ? 1.0f : 0.0f) };
        const float wzv[2] = { (1.0f - zd) * (((unsigned)iz[0] < (unsigned)DD) ? 1.0f : 0.0f),
                               zd          * (((unsigned)iz[1] < (unsigned)DD) ? 1.0f : 0.0f) };
        const unsigned ox[2] = { (unsigned)(min(max(ix[0], 0), HH - 1) * (WW * DD * CC)),
                                 (unsigned)(min(max(ix[1], 0), HH - 1) * (WW * DD * CC)) };
        const unsigned oy[2] = { (unsigned)(min(max(iy[0], 0), WW - 1) * (DD * CC)),
                                 (unsigned)(min(max(iy[1], 0), WW - 1) * (DD * CC)) };
        const unsigned oz[2] = { (unsigned)(min(max(iz[0], 0), DD - 1) * CC),
                                 (unsigned)(min(max(iz[1], 0), DD - 1) * CC) };
        #pragma unroll
        for (int i = 0; i < 8; ++i) {
            const int bx = (i >> 2) & 1, by = (i >> 1) & 1, bz = i & 1;
            off[v][i] = ox[bx] + oy[by] + oz[bz];
            wgt[v][i] = wxv[bx] * wyv[by] * wzv[bz];
        }
    };
    auto load = [&](int v) {
        #pragma unroll
        for (int i = 0; i < 8; ++i)
            c[v][i] = *(const fx4*)(base + off[v][i]);
    };
    auto accst = [&](int v) {
        fx4 acc = (fx4){0.f, 0.f, 0.f, 0.f};
        #pragma unroll
        for (int i = 0; i < 8; ++i) {
            acc.x = fmaf(wgt[v][i], c[v][i].x, acc.x);
            acc.y = fmaf(wgt[v][i], c[v][i].y, acc.y);
            acc.z = fmaf(wgt[v][i], c[v][i].z, acc.z);
            acc.w = fmaf(wgt[v][i], c[v][i].w, acc.w);
        }
        __builtin_nontemporal_store(acc, (fx4*)(obase + v * (WW * DD * CC)));
    };

    // 2-deep software pipeline
    calc(0); load(0);
    calc(1); load(1);
    calc(2); load(2);
    accst(0);
    calc(3); load(3);
    accst(1);
    accst(2);
    accst(3);
}

extern "C" void kernel_launch(void* const* d_in, const int* in_sizes, int n_in,
                              void* d_out, int out_size, void* d_ws, size_t ws_size,
                              hipStream_t stream) {
    const float* fmap  = (const float*)d_in[0];
    const float* theta = (const float*)d_in[1];
    float* out = (float*)d_out;

    const int total_blocks = BB * PP * 64;   // 4096 blocks, 512 voxels each (4/thread)
    resample_kernel<<<dim3(total_blocks), dim3(256), 0, stream>>>(fmap, theta, out);
}

// Round 6
// 120.804 us; speedup vs baseline: 1.0452x; 1.0452x over previous
//
#include <hip/hip_runtime.h>
#include <cstddef>

#define BB 16
#define PP 4
#define HH 32
#define WW 32
#define DD 32
#define CC 8

typedef float fx4 __attribute__((ext_vector_type(4)));

// Two voxels per thread (h0, h0+1), one 4-channel half each. All 16 float4
// loads are issued before any FMA, enforced with sched_barrier(0) so the
// compiler cannot re-serialize them (R5 post-mortem: it rematerialized the
// pipeline down to VGPR=36, leaving ~2 loads in flight).
// Branch-free: clamped addresses, zeroed weights for out-of-volume corners.
__global__ __launch_bounds__(256) void resample_kernel(
    const float* __restrict__ fmap,
    const float* __restrict__ theta,
    float* __restrict__ out)
{
    const int bp   = blockIdx.x >> 7;            // 128 blocks per (b,p)
    const int idx  = blockIdx.x & 127;
    const int h0   = (idx >> 3) << 1;            // 16 h-pairs
    const int w0   = (idx & 7) << 2;             // 8 w-quads
    const int tid  = threadIdx.x;
    const int half = tid & 1;                    // which float4 of the 8 channels
    const int d    = (tid >> 1) & 31;
    const int w    = w0 + (tid >> 6);            // one w per wave

    const float* th = theta + bp * 12;
    const float t0 = th[0], t1 = th[1], t2 = th[2],  t3  = th[3];
    const float t4 = th[4], t5 = th[5], t6 = th[6],  t7  = th[7];
    const float t8 = th[8], t9 = th[9], t10 = th[10], t11 = th[11];

    const float fw = (float)w, fd = (float)d;
    const float* __restrict__ base = fmap + (size_t)bp * (HH * WW * DD * CC) + half * 4;

    unsigned off[2][8];
    float    wgt[2][8];

    #pragma unroll
    for (int v = 0; v < 2; ++v) {
        const float fh = (float)(h0 + v);
        // meshgrid 'xy': grid point is (x=w, y=h, z=d); +2 pad offset
        const float x = fmaf(t0, fw, fmaf(t1, fh, fmaf(t2,  fd, t3 ))) + 2.0f;
        const float y = fmaf(t4, fw, fmaf(t5, fh, fmaf(t6,  fd, t7 ))) + 2.0f;
        const float z = fmaf(t8, fw, fmaf(t9, fh, fmaf(t10, fd, t11))) + 2.0f;

        // faithful: floor -> clip to [0, H+2] in padded coords (all axes H+2)
        const int x0 = min(max((int)floorf(x), 0), HH + 2);
        const int y0 = min(max((int)floorf(y), 0), HH + 2);
        const int z0 = min(max((int)floorf(z), 0), HH + 2);
        const float xd = x - (float)x0, yd = y - (float)y0, zd = z - (float)z0;

        const int ix[2] = { x0 - 2, x0 - 1 };    // x indexes the H axis (ref quirk)
        const int iy[2] = { y0 - 2, y0 - 1 };
        const int iz[2] = { z0 - 2, z0 - 1 };
        const float wxv[2] = { (1.0f - xd) * (((unsigned)ix[0] < (unsigned)HH) ? 1.0f : 0.0f),
                               xd          * (((unsigned)ix[1] < (unsigned)HH) ? 1.0f : 0.0f) };
        const float wyv[2] = { (1.0f - yd) * (((unsigned)iy[0] < (unsigned)WW) ? 1.0f : 0.0f),
                               yd          * (((unsigned)iy[1] < (unsigned)WW) ? 1.0f : 0.0f) };
        const float wzv[2] = { (1.0f - zd) * (((unsigned)iz[0] < (unsigned)DD) ? 1.0f : 0.0f),
                               zd          * (((unsigned)iz[1] < (unsigned)DD) ? 1.0f : 0.0f) };
        const unsigned ox[2] = { (unsigned)(min(max(ix[0], 0), HH - 1) * (WW * DD * CC)),
                                 (unsigned)(min(max(ix[1], 0), HH - 1) * (WW * DD * CC)) };
        const unsigned oy[2] = { (unsigned)(min(max(iy[0], 0), WW - 1) * (DD * CC)),
                                 (unsigned)(min(max(iy[1], 0), WW - 1) * (DD * CC)) };
        const unsigned oz[2] = { (unsigned)(min(max(iz[0], 0), DD - 1) * CC),
                                 (unsigned)(min(max(iz[1], 0), DD - 1) * CC) };

        #pragma unroll
        for (int i = 0; i < 8; ++i) {
            const int bx = (i >> 2) & 1, by = (i >> 1) & 1, bz = i & 1;
            off[v][i] = ox[bx] + oy[by] + oz[bz];
            wgt[v][i] = wxv[bx] * wyv[by] * wzv[bz];
        }
    }

    // ---- load phase: 16 independent global_load_dwordx4, all in flight ----
    fx4 c[2][8];
    #pragma unroll
    for (int v = 0; v < 2; ++v)
        #pragma unroll
        for (int i = 0; i < 8; ++i)
            c[v][i] = *(const fx4*)(base + off[v][i]);

    // Hard scheduling fence: nothing (esp. the FMA uses and their waitcnts)
    // may be hoisted above this point; loads stay batched.
    __builtin_amdgcn_sched_barrier(0);

    // ---- consume phase ----
    #pragma unroll
    for (int v = 0; v < 2; ++v) {
        fx4 acc = (fx4){0.f, 0.f, 0.f, 0.f};
        #pragma unroll
        for (int i = 0; i < 8; ++i) {
            acc.x = fmaf(wgt[v][i], c[v][i].x, acc.x);
            acc.y = fmaf(wgt[v][i], c[v][i].y, acc.y);
            acc.z = fmaf(wgt[v][i], c[v][i].z, acc.z);
            acc.w = fmaf(wgt[v][i], c[v][i].w, acc.w);
        }
        const int vox = (((h0 + v) * WW) + w) * DD + d;
        fx4* o = (fx4*)(out + (size_t)(bp * (HH * WW * DD) + vox) * CC + half * 4);
        __builtin_nontemporal_store(acc, o);
    }
}

extern "C" void kernel_launch(void* const* d_in, const int* in_sizes, int n_in,
                              void* d_out, int out_size, void* d_ws, size_t ws_size,
                              hipStream_t stream) {
    const float* fmap  = (const float*)d_in[0];
    const float* theta = (const float*)d_in[1];
    float* out = (float*)d_out;

    const int total_blocks = BB * PP * 128;   // 16384 voxel-pairs -> 2 voxels/thread
    resample_kernel<<<dim3(total_blocks), dim3(256), 0, stream>>>(fmap, theta, out);
}